// Round 5
// baseline (535.697 us; speedup 1.0000x reference)
//
#include <hip/hip_runtime.h>
#include <hip/hip_bf16.h>

#define N_NODES 100000
#define N_EDGES 1600000
#define IN_DIM 128
#define HID_DIM 256
#define LN_EPS 1e-5f
#define NT (N_NODES / 16)              // 6250 16-row tiles, exact
#define CHUNK 8                        // tiles per barrier round (128 rows)
#define NCHUNK ((NT + CHUNK - 1) / CHUNK)

typedef short bf16x8 __attribute__((ext_vector_type(8)));
typedef float f32x4  __attribute__((ext_vector_type(4)));

static __device__ __forceinline__ short f2bf(float x) {
    return __builtin_bit_cast(short, __float2bfloat16(x));  // RNE round
}

// ---------------------------------------------------------------------------
// Kernel 1: degree counts
// ---------------------------------------------------------------------------
__global__ void deg_kernel(const int* __restrict__ src, const int* __restrict__ dst,
                           unsigned* __restrict__ deg_out, unsigned* __restrict__ deg_in) {
    int e = blockIdx.x * blockDim.x + threadIdx.x;
    if (e < N_EDGES) {
        atomicAdd(&deg_out[src[e]], 1u);
        atomicAdd(&deg_in[dst[e]], 1u);
    }
}

// ---------------------------------------------------------------------------
// Kernel 2: single-block exclusive scan (4 elems/thread) -> row_ptr
// ---------------------------------------------------------------------------
__global__ __launch_bounds__(1024)
void scan_kernel(const unsigned* __restrict__ deg_in, unsigned* __restrict__ row_ptr) {
    __shared__ unsigned wsum[16];
    __shared__ unsigned carry_s;
    if (threadIdx.x == 0) carry_s = 0;
    __syncthreads();
    const int lane = threadIdx.x & 63;
    const int wid  = threadIdx.x >> 6;
    for (int base = 0; base < N_NODES; base += 4096) {
        int i0 = base + threadIdx.x * 4;
        unsigned d0 = 0, d1 = 0, d2 = 0, d3 = 0;
        if (i0 < N_NODES) {
            uint4 v = *(const uint4*)(deg_in + i0);
            d0 = v.x; d1 = v.y; d2 = v.z; d3 = v.w;
        }
        unsigned t = d0 + d1 + d2 + d3;
        unsigned x = t;
        #pragma unroll
        for (int d = 1; d < 64; d <<= 1) {
            unsigned tt = __shfl_up(x, d, 64);
            if (lane >= d) x += tt;
        }
        if (lane == 63) wsum[wid] = x;
        __syncthreads();
        if (threadIdx.x == 0) {
            unsigned run = carry_s;
            #pragma unroll
            for (int w = 0; w < 16; ++w) { unsigned tmp = wsum[w]; wsum[w] = run; run += tmp; }
            carry_s = run;
        }
        __syncthreads();
        if (i0 < N_NODES) {
            unsigned b = wsum[wid] + (x - t);
            uint4 rp;
            rp.x = b; rp.y = b + d0; rp.z = b + d0 + d1; rp.w = b + d0 + d1 + d2;
            *(uint4*)(row_ptr + i0) = rp;
        }
        __syncthreads();
    }
    if (threadIdx.x == 0) row_ptr[N_NODES] = carry_s;
}

// ---------------------------------------------------------------------------
// Kernel 3: CSR fill (bucket edges by dst)
// ---------------------------------------------------------------------------
__global__ void fill_kernel(const int* __restrict__ src, const int* __restrict__ dst,
                            const unsigned* __restrict__ row_ptr,
                            unsigned* __restrict__ fill, unsigned* __restrict__ edge_src) {
    int e = blockIdx.x * blockDim.x + threadIdx.x;
    if (e < N_EDGES) {
        int d = dst[e];
        unsigned pos = row_ptr[d] + atomicAdd(&fill[d], 1u);
        edge_src[pos] = (unsigned)src[e];
    }
}

// ---------------------------------------------------------------------------
// Kernel 4: W / skipW -> bf16, transposed to [HID_DIM][IN_DIM]
// ---------------------------------------------------------------------------
__global__ void wcvt_kernel(const float* __restrict__ W, const float* __restrict__ sW,
                            ushort* __restrict__ Wt, ushort* __restrict__ sWt) {
    int id = blockIdx.x * blockDim.x + threadIdx.x;
    if (id < IN_DIM * HID_DIM) {
        int k = id & (IN_DIM - 1);
        int n = id >> 7;
        Wt[n * IN_DIM + k]  = (ushort)f2bf(W[k * HID_DIM + n]);
        sWt[n * IN_DIM + k] = (ushort)f2bf(sW[k * HID_DIM + n]);
    }
}

// ---------------------------------------------------------------------------
// Kernel 5: featn = bf16(feat * norm_src)
// ---------------------------------------------------------------------------
__global__ void fcvt_kernel(const float* __restrict__ feat,
                            const unsigned* __restrict__ deg_out,
                            ushort* __restrict__ featn) {
    int id = blockIdx.x * blockDim.x + threadIdx.x;
    if (id < N_NODES * (IN_DIM / 4)) {
        int row = id >> 5;
        float ns = rsqrtf(fmaxf((float)deg_out[row], 1.f));
        float4 v = ((const float4*)feat)[id];
        ushort4 o;
        o.x = (ushort)f2bf(v.x * ns);
        o.y = (ushort)f2bf(v.y * ns);
        o.z = (ushort)f2bf(v.z * ns);
        o.w = (ushort)f2bf(v.w * ns);
        ((ushort4*)featn)[id] = o;
    }
}

// ---------------------------------------------------------------------------
// Kernel 6: row-per-wave gather SpMM over bf16 featn -> aggb (bf16)
// ---------------------------------------------------------------------------
__global__ __launch_bounds__(256)
void spmm_kernel(const ushort* __restrict__ featn,
                 const unsigned* __restrict__ row_ptr, const unsigned* __restrict__ edge_src,
                 unsigned* __restrict__ aggb_u32) {
    int gw = (blockIdx.x * 256 + threadIdx.x) >> 6;
    int lane = threadIdx.x & 63;
    if (gw >= N_NODES) return;
    unsigned beg = row_ptr[gw], end = row_ptr[gw + 1];
    float a0 = 0.f, a1 = 0.f;
    unsigned e = beg;
    for (; e + 4 <= end; e += 4) {
        unsigned s0 = edge_src[e + 0];
        unsigned s1 = edge_src[e + 1];
        unsigned s2 = edge_src[e + 2];
        unsigned s3 = edge_src[e + 3];
        unsigned v0 = *(const unsigned*)(featn + (size_t)s0 * IN_DIM + 2 * lane);
        unsigned v1 = *(const unsigned*)(featn + (size_t)s1 * IN_DIM + 2 * lane);
        unsigned v2 = *(const unsigned*)(featn + (size_t)s2 * IN_DIM + 2 * lane);
        unsigned v3 = *(const unsigned*)(featn + (size_t)s3 * IN_DIM + 2 * lane);
        a0 += __builtin_bit_cast(float, v0 << 16);
        a1 += __builtin_bit_cast(float, v0 & 0xffff0000u);
        a0 += __builtin_bit_cast(float, v1 << 16);
        a1 += __builtin_bit_cast(float, v1 & 0xffff0000u);
        a0 += __builtin_bit_cast(float, v2 << 16);
        a1 += __builtin_bit_cast(float, v2 & 0xffff0000u);
        a0 += __builtin_bit_cast(float, v3 << 16);
        a1 += __builtin_bit_cast(float, v3 & 0xffff0000u);
    }
    for (; e < end; ++e) {
        unsigned s = edge_src[e];
        unsigned v = *(const unsigned*)(featn + (size_t)s * IN_DIM + 2 * lane);
        a0 += __builtin_bit_cast(float, v << 16);
        a1 += __builtin_bit_cast(float, v & 0xffff0000u);
    }
    float nd = rsqrtf(fmaxf((float)(end - beg), 1.0f));
    unsigned lo = (unsigned)(ushort)f2bf(a0 * nd);
    unsigned hi = (unsigned)(ushort)f2bf(a1 * nd);
    aggb_u32[(size_t)gw * (IN_DIM / 2) + lane] = lo | (hi << 16);
}

// ---------------------------------------------------------------------------
// Kernel 7: MFMA GEMM1 + LN + ReLU + MFMA GEMM2 + biases -> out
// 16 waves; wave w owns col-strip [w*16,w*16+16), B frags in registers.
// CHUNK=8 tiles (128 rows) per barrier round: phase1 computes GEMM1 for all
// 8 tiles (acc[8] live), one barrier, cross-wave LN reduce for 128 rows,
// one barrier, phase2 does LN+ReLU+GEMM2+store. 2 barriers per 128 rows.
// ---------------------------------------------------------------------------
__global__ __launch_bounds__(1024)
void gemm_kernel(const ushort* __restrict__ aggb, const float* __restrict__ feat,
                 const ushort* __restrict__ Wt, const ushort* __restrict__ sWt,
                 const float* __restrict__ bvec, const float* __restrict__ gamma,
                 const float* __restrict__ beta, const float* __restrict__ skipb,
                 float* __restrict__ out) {
    __shared__ float2 red[128][17];   // [row-in-chunk][wave] strip partials, padded
    __shared__ float2 mures[128];     // per-row (mu, rstd)
    const int tid  = threadIdx.x;
    const int w    = tid >> 6;       // wave 0..15
    const int lane = tid & 63;
    const int c    = lane & 15;
    const int g    = lane >> 4;
    const int col  = w * 16 + c;     // fixed output column

    const float bb = bvec[col], ga = gamma[col], be = beta[col], sb = skipb[col];

    bf16x8 bW[4], bS[4];
    #pragma unroll
    for (int ks = 0; ks < 4; ++ks) {
        bW[ks] = *(const bf16x8*)(Wt  + (size_t)col * IN_DIM + ks * 32 + g * 8);
        bS[ks] = *(const bf16x8*)(sWt + (size_t)col * IN_DIM + ks * 32 + g * 8);
    }

    for (int chunk = blockIdx.x; chunk < NCHUNK; chunk += gridDim.x) {
        const int tile0 = chunk * CHUNK;
        f32x4 acc[CHUNK];

        // ---- phase 1: GEMM1 for 8 tiles + strip LN partials ----------------
        #pragma unroll
        for (int t = 0; t < CHUNK; ++t) {
            if (tile0 + t < NT) {
                const int r0 = (tile0 + t) * 16;
                f32x4 a4 = (f32x4){bb, bb, bb, bb};
                #pragma unroll
                for (int ks = 0; ks < 4; ++ks) {
                    bf16x8 a = *(const bf16x8*)(aggb + (size_t)(r0 + c) * IN_DIM + ks * 32 + g * 8);
                    a4 = __builtin_amdgcn_mfma_f32_16x16x32_bf16(a, bW[ks], a4, 0, 0, 0);
                }
                acc[t] = a4;
                float s1[4], s2[4];
                #pragma unroll
                for (int j = 0; j < 4; ++j) { s1[j] = a4[j]; s2[j] = a4[j] * a4[j]; }
                #pragma unroll
                for (int m = 1; m <= 8; m <<= 1) {
                    #pragma unroll
                    for (int j = 0; j < 4; ++j) {
                        s1[j] += __shfl_xor(s1[j], m, 64);
                        s2[j] += __shfl_xor(s2[j], m, 64);
                    }
                }
                if (c == 0) {
                    #pragma unroll
                    for (int j = 0; j < 4; ++j)
                        red[t * 16 + g * 4 + j][w] = make_float2(s1[j], s2[j]);
                }
            }
        }
        __syncthreads();

        // ---- cross-wave LN reduce: 128 rows x 16 partials -------------------
        {
            const int row = tid >> 3;       // 0..127
            const int p   = tid & 7;
            float2 v1 = red[row][p];
            float2 v2 = red[row][p + 8];
            float t1 = v1.x + v2.x;
            float t2 = v1.y + v2.y;
            #pragma unroll
            for (int m = 1; m <= 4; m <<= 1) {
                t1 += __shfl_xor(t1, m, 64);
                t2 += __shfl_xor(t2, m, 64);
            }
            if (p == 0) {
                float mu  = t1 * (1.f / HID_DIM);
                float var = t2 * (1.f / HID_DIM) - mu * mu;
                mures[row] = make_float2(mu, rsqrtf(var + LN_EPS));
            }
        }
        __syncthreads();

        // ---- phase 2: LN + ReLU + GEMM2 + store ------------------------------
        #pragma unroll
        for (int t = 0; t < CHUNK; ++t) {
            if (tile0 + t < NT) {
                const int r0 = (tile0 + t) * 16;
                f32x4 a4 = acc[t];
                #pragma unroll
                for (int j = 0; j < 4; ++j) {
                    float2 mr = mures[t * 16 + g * 4 + j];
                    a4[j] = fmaxf(fmaf((a4[j] - mr.x) * mr.y, ga, be), 0.f);
                }
                #pragma unroll
                for (int ks = 0; ks < 4; ++ks) {
                    const float* fp = feat + (size_t)(r0 + c) * IN_DIM + ks * 32 + g * 8;
                    float4 u = *(const float4*)fp;
                    float4 v = *(const float4*)(fp + 4);
                    bf16x8 a;
                    a[0] = f2bf(u.x); a[1] = f2bf(u.y); a[2] = f2bf(u.z); a[3] = f2bf(u.w);
                    a[4] = f2bf(v.x); a[5] = f2bf(v.y); a[6] = f2bf(v.z); a[7] = f2bf(v.w);
                    a4 = __builtin_amdgcn_mfma_f32_16x16x32_bf16(a, bS[ks], a4, 0, 0, 0);
                }
                #pragma unroll
                for (int j = 0; j < 4; ++j)
                    out[(size_t)(r0 + g * 4 + j) * HID_DIM + col] = a4[j] + sb;
            }
        }
    }
}

// ---------------------------------------------------------------------------
extern "C" void kernel_launch(void* const* d_in, const int* in_sizes, int n_in,
                              void* d_out, int out_size, void* d_ws, size_t ws_size,
                              hipStream_t stream) {
    const float* feat  = (const float*)d_in[0];
    const int*   src   = (const int*)d_in[1];
    const int*   dst   = (const int*)d_in[2];
    const float* W     = (const float*)d_in[3];
    const float* bvec  = (const float*)d_in[4];
    const float* gamma = (const float*)d_in[5];
    const float* beta  = (const float*)d_in[6];
    const float* skipW = (const float*)d_in[7];
    const float* skipb = (const float*)d_in[8];
    float* out = (float*)d_out;

    // workspace layout (≈59.4 MB)
    char* ws = (char*)d_ws;
    ushort*   aggb     = (ushort*)ws;                             // N*128 bf16 = 25.6 MB
    ushort*   featn    = aggb + (size_t)N_NODES * IN_DIM;         // N*128 bf16 = 25.6 MB
    ushort*   Wt       = featn + (size_t)N_NODES * IN_DIM;        // 32768 bf16
    ushort*   sWt      = Wt + IN_DIM * HID_DIM;                   // 32768 bf16
    unsigned* deg_out  = (unsigned*)(sWt + IN_DIM * HID_DIM);     // N
    unsigned* deg_in   = deg_out + N_NODES;                       // N
    unsigned* fill     = deg_in + N_NODES;                        // N
    unsigned* row_ptr  = fill + N_NODES;                          // N+4
    unsigned* edge_src = row_ptr + N_NODES + 4;                   // E

    hipMemsetAsync(deg_out, 0, (size_t)3 * N_NODES * 4, stream);

    deg_kernel<<<(N_EDGES + 255) / 256, 256, 0, stream>>>(src, dst, deg_out, deg_in);

    wcvt_kernel<<<(IN_DIM * HID_DIM + 255) / 256, 256, 0, stream>>>(W, skipW, Wt, sWt);

    scan_kernel<<<1, 1024, 0, stream>>>(deg_in, row_ptr);

    fill_kernel<<<(N_EDGES + 255) / 256, 256, 0, stream>>>(src, dst, row_ptr, fill, edge_src);

    fcvt_kernel<<<(N_NODES * (IN_DIM / 4) + 255) / 256, 256, 0, stream>>>(feat, deg_out, featn);

    spmm_kernel<<<(N_NODES * 64 + 255) / 256, 256, 0, stream>>>(featn, row_ptr, edge_src,
                                                                (unsigned*)aggb);

    gemm_kernel<<<512, 1024, 0, stream>>>(aggb, feat, Wt, sWt, bvec, gamma, beta, skipb, out);
}

// Round 6
// 525.257 us; speedup vs baseline: 1.0199x; 1.0199x over previous
//
#include <hip/hip_runtime.h>
#include <hip/hip_bf16.h>

#define N_NODES 100000
#define N_EDGES 1600000
#define IN_DIM 128
#define HID_DIM 256
#define LN_EPS 1e-5f
#define NT (N_NODES / 16)   // 6250 16-row tiles, exact

typedef short bf16x8 __attribute__((ext_vector_type(8)));
typedef float f32x4  __attribute__((ext_vector_type(4)));

static __device__ __forceinline__ short f2bf(float x) {
    return __builtin_bit_cast(short, __float2bfloat16(x));  // RNE round
}
static __device__ __forceinline__ float bf2f(ushort u) {
    return __builtin_bit_cast(float, ((unsigned)u) << 16);
}

// ---------------------------------------------------------------------------
// Kernel 1: degree counts
// ---------------------------------------------------------------------------
__global__ void deg_kernel(const int* __restrict__ src, const int* __restrict__ dst,
                           unsigned* __restrict__ deg_out, unsigned* __restrict__ deg_in) {
    int e = blockIdx.x * blockDim.x + threadIdx.x;
    if (e < N_EDGES) {
        atomicAdd(&deg_out[src[e]], 1u);
        atomicAdd(&deg_in[dst[e]], 1u);
    }
}

// ---------------------------------------------------------------------------
// Kernel 2: single-block exclusive scan (4 elems/thread) -> row_ptr
// ---------------------------------------------------------------------------
__global__ __launch_bounds__(1024)
void scan_kernel(const unsigned* __restrict__ deg_in, unsigned* __restrict__ row_ptr) {
    __shared__ unsigned wsum[16];
    __shared__ unsigned carry_s;
    if (threadIdx.x == 0) carry_s = 0;
    __syncthreads();
    const int lane = threadIdx.x & 63;
    const int wid  = threadIdx.x >> 6;
    for (int base = 0; base < N_NODES; base += 4096) {
        int i0 = base + threadIdx.x * 4;
        unsigned d0 = 0, d1 = 0, d2 = 0, d3 = 0;
        if (i0 < N_NODES) {
            uint4 v = *(const uint4*)(deg_in + i0);
            d0 = v.x; d1 = v.y; d2 = v.z; d3 = v.w;
        }
        unsigned t = d0 + d1 + d2 + d3;
        unsigned x = t;
        #pragma unroll
        for (int d = 1; d < 64; d <<= 1) {
            unsigned tt = __shfl_up(x, d, 64);
            if (lane >= d) x += tt;
        }
        if (lane == 63) wsum[wid] = x;
        __syncthreads();
        if (threadIdx.x == 0) {
            unsigned run = carry_s;
            #pragma unroll
            for (int w = 0; w < 16; ++w) { unsigned tmp = wsum[w]; wsum[w] = run; run += tmp; }
            carry_s = run;
        }
        __syncthreads();
        if (i0 < N_NODES) {
            unsigned b = wsum[wid] + (x - t);
            uint4 rp;
            rp.x = b; rp.y = b + d0; rp.z = b + d0 + d1; rp.w = b + d0 + d1 + d2;
            *(uint4*)(row_ptr + i0) = rp;
        }
        __syncthreads();
    }
    if (threadIdx.x == 0) row_ptr[N_NODES] = carry_s;
}

// ---------------------------------------------------------------------------
// Kernel 3: CSR fill (bucket edges by dst)
// ---------------------------------------------------------------------------
__global__ void fill_kernel(const int* __restrict__ src, const int* __restrict__ dst,
                            const unsigned* __restrict__ row_ptr,
                            unsigned* __restrict__ fill, unsigned* __restrict__ edge_src) {
    int e = blockIdx.x * blockDim.x + threadIdx.x;
    if (e < N_EDGES) {
        int d = dst[e];
        unsigned pos = row_ptr[d] + atomicAdd(&fill[d], 1u);
        edge_src[pos] = (unsigned)src[e];
    }
}

// ---------------------------------------------------------------------------
// Kernel 4: W / skipW -> bf16 in MFMA B-FRAGMENT-MAJOR order:
// frag u = (n*4+ks)*64 + lane; elem j = W[(ks*32+g*8+j)*256 + n*16+c]
// so the GEMM kernels stage B into LDS with a linear copy.
// ---------------------------------------------------------------------------
__global__ void wcvt_kernel(const float* __restrict__ W, const float* __restrict__ sW,
                            ushort* __restrict__ Wfrag, ushort* __restrict__ sWfrag) {
    int tid = blockIdx.x * blockDim.x + threadIdx.x;
    if (tid >= 8192) return;
    const float* srcm = (tid < 4096) ? W : sW;
    ushort* dstm = (tid < 4096) ? Wfrag : sWfrag;
    int u = tid & 4095;
    int lane = u & 63;
    int ks = (u >> 6) & 3;
    int n = u >> 8;
    int c = lane & 15, g = lane >> 4;
    int col = n * 16 + c;
    int k0 = ks * 32 + g * 8;
    ushort4 lo, hi;
    lo.x = (ushort)f2bf(srcm[(size_t)(k0 + 0) * HID_DIM + col]);
    lo.y = (ushort)f2bf(srcm[(size_t)(k0 + 1) * HID_DIM + col]);
    lo.z = (ushort)f2bf(srcm[(size_t)(k0 + 2) * HID_DIM + col]);
    lo.w = (ushort)f2bf(srcm[(size_t)(k0 + 3) * HID_DIM + col]);
    hi.x = (ushort)f2bf(srcm[(size_t)(k0 + 4) * HID_DIM + col]);
    hi.y = (ushort)f2bf(srcm[(size_t)(k0 + 5) * HID_DIM + col]);
    hi.z = (ushort)f2bf(srcm[(size_t)(k0 + 6) * HID_DIM + col]);
    hi.w = (ushort)f2bf(srcm[(size_t)(k0 + 7) * HID_DIM + col]);
    *(ushort4*)(dstm + (size_t)u * 8)     = lo;
    *(ushort4*)(dstm + (size_t)u * 8 + 4) = hi;
}

// ---------------------------------------------------------------------------
// Kernel 5: featn = bf16(feat * norm_src)
// ---------------------------------------------------------------------------
__global__ void fcvt_kernel(const float* __restrict__ feat,
                            const unsigned* __restrict__ deg_out,
                            ushort* __restrict__ featn) {
    int id = blockIdx.x * blockDim.x + threadIdx.x;
    if (id < N_NODES * (IN_DIM / 4)) {
        int row = id >> 5;
        float ns = rsqrtf(fmaxf((float)deg_out[row], 1.f));
        float4 v = ((const float4*)feat)[id];
        ushort4 o;
        o.x = (ushort)f2bf(v.x * ns);
        o.y = (ushort)f2bf(v.y * ns);
        o.z = (ushort)f2bf(v.z * ns);
        o.w = (ushort)f2bf(v.w * ns);
        ((ushort4*)featn)[id] = o;
    }
}

// ---------------------------------------------------------------------------
// Kernel 6: row-per-wave gather SpMM over bf16 featn -> aggb (bf16)
// ---------------------------------------------------------------------------
__global__ __launch_bounds__(256)
void spmm_kernel(const ushort* __restrict__ featn,
                 const unsigned* __restrict__ row_ptr, const unsigned* __restrict__ edge_src,
                 unsigned* __restrict__ aggb_u32) {
    int gw = (blockIdx.x * 256 + threadIdx.x) >> 6;
    int lane = threadIdx.x & 63;
    if (gw >= N_NODES) return;
    unsigned beg = row_ptr[gw], end = row_ptr[gw + 1];
    float a0 = 0.f, a1 = 0.f;
    unsigned e = beg;
    for (; e + 4 <= end; e += 4) {
        unsigned s0 = edge_src[e + 0];
        unsigned s1 = edge_src[e + 1];
        unsigned s2 = edge_src[e + 2];
        unsigned s3 = edge_src[e + 3];
        unsigned v0 = *(const unsigned*)(featn + (size_t)s0 * IN_DIM + 2 * lane);
        unsigned v1 = *(const unsigned*)(featn + (size_t)s1 * IN_DIM + 2 * lane);
        unsigned v2 = *(const unsigned*)(featn + (size_t)s2 * IN_DIM + 2 * lane);
        unsigned v3 = *(const unsigned*)(featn + (size_t)s3 * IN_DIM + 2 * lane);
        a0 += __builtin_bit_cast(float, v0 << 16);
        a1 += __builtin_bit_cast(float, v0 & 0xffff0000u);
        a0 += __builtin_bit_cast(float, v1 << 16);
        a1 += __builtin_bit_cast(float, v1 & 0xffff0000u);
        a0 += __builtin_bit_cast(float, v2 << 16);
        a1 += __builtin_bit_cast(float, v2 & 0xffff0000u);
        a0 += __builtin_bit_cast(float, v3 << 16);
        a1 += __builtin_bit_cast(float, v3 & 0xffff0000u);
    }
    for (; e < end; ++e) {
        unsigned s = edge_src[e];
        unsigned v = *(const unsigned*)(featn + (size_t)s * IN_DIM + 2 * lane);
        a0 += __builtin_bit_cast(float, v << 16);
        a1 += __builtin_bit_cast(float, v & 0xffff0000u);
    }
    float nd = rsqrtf(fmaxf((float)(end - beg), 1.0f));
    unsigned lo = (unsigned)(ushort)f2bf(a0 * nd);
    unsigned hi = (unsigned)(ushort)f2bf(a1 * nd);
    aggb_u32[(size_t)gw * (IN_DIM / 2) + lane] = lo | (hi << 16);
}

// ---------------------------------------------------------------------------
// Kernel 7: GEMM1 + LN + ReLU -> lnb (bf16, MFMA C-fragment layout)
// 512 threads = 8 waves. B (64KB fragment-major) staged once in LDS.
// Each wave independently owns 16 rows x 256 cols per tile -> in-wave LN,
// ZERO barriers in the main loop.
// ---------------------------------------------------------------------------
__global__ __launch_bounds__(512, 2)
void gemm1_ln_kernel(const ushort* __restrict__ aggb, const ushort* __restrict__ Wfrag,
                     const float* __restrict__ bvec, const float* __restrict__ gamma,
                     const float* __restrict__ beta, ushort* __restrict__ lnb) {
    __shared__ __align__(16) ushort Blds[32768];   // 64 KB
    const int tid = threadIdx.x;
    #pragma unroll
    for (int i = 0; i < 8; ++i)
        ((uint4*)Blds)[tid + i * 512] = ((const uint4*)Wfrag)[tid + i * 512];
    __syncthreads();

    const int lane = tid & 63;
    const int c = lane & 15, g = lane >> 4;
    const int gw = blockIdx.x * 8 + (tid >> 6);

    float bb[16], ga[16], be[16];
    #pragma unroll
    for (int n = 0; n < 16; ++n) {
        bb[n] = bvec[n * 16 + c];
        ga[n] = gamma[n * 16 + c];
        be[n] = beta[n * 16 + c];
    }

    for (int t = gw; t < NT; t += 4096) {
        const int r0 = t * 16;
        bf16x8 A[4];
        #pragma unroll
        for (int ks = 0; ks < 4; ++ks)
            A[ks] = *(const bf16x8*)(aggb + (size_t)(r0 + c) * IN_DIM + ks * 32 + g * 8);

        f32x4 acc[16];
        #pragma unroll
        for (int n = 0; n < 16; ++n) {
            acc[n] = (f32x4){bb[n], bb[n], bb[n], bb[n]};
            #pragma unroll
            for (int ks = 0; ks < 4; ++ks) {
                bf16x8 b = *(const bf16x8*)(Blds + ((n * 4 + ks) * 64 + lane) * 8);
                acc[n] = __builtin_amdgcn_mfma_f32_16x16x32_bf16(A[ks], b, acc[n], 0, 0, 0);
            }
        }

        // in-wave LayerNorm over 256 cols (16 regs x 16 lanes per g-group)
        float s1[4], s2[4];
        #pragma unroll
        for (int j = 0; j < 4; ++j) { s1[j] = 0.f; s2[j] = 0.f; }
        #pragma unroll
        for (int n = 0; n < 16; ++n) {
            #pragma unroll
            for (int j = 0; j < 4; ++j) {
                s1[j] += acc[n][j];
                s2[j] = fmaf(acc[n][j], acc[n][j], s2[j]);
            }
        }
        #pragma unroll
        for (int m = 1; m <= 8; m <<= 1) {
            #pragma unroll
            for (int j = 0; j < 4; ++j) {
                s1[j] += __shfl_xor(s1[j], m, 64);
                s2[j] += __shfl_xor(s2[j], m, 64);
            }
        }
        float mu[4], rstd[4];
        #pragma unroll
        for (int j = 0; j < 4; ++j) {
            mu[j] = s1[j] * (1.f / HID_DIM);
            float var = s2[j] * (1.f / HID_DIM) - mu[j] * mu[j];
            rstd[j] = rsqrtf(var + LN_EPS);
        }

        #pragma unroll
        for (int n = 0; n < 16; ++n) {
            ushort4 o;
            o.x = (ushort)f2bf(fmaxf(fmaf((acc[n][0] - mu[0]) * rstd[0], ga[n], be[n]), 0.f));
            o.y = (ushort)f2bf(fmaxf(fmaf((acc[n][1] - mu[1]) * rstd[1], ga[n], be[n]), 0.f));
            o.z = (ushort)f2bf(fmaxf(fmaf((acc[n][2] - mu[2]) * rstd[2], ga[n], be[n]), 0.f));
            o.w = (ushort)f2bf(fmaxf(fmaf((acc[n][3] - mu[3]) * rstd[3], ga[n], be[n]), 0.f));
            *(ushort4*)(lnb + ((size_t)(t * 16 + n) * 64 + lane) * 4) = o;
        }
    }
}

// ---------------------------------------------------------------------------
// Kernel 8: GEMM2 (feat @ skipW) + lnb + skip_b -> out (f32 row-major)
// Same structure as kernel 7; acc initialized from lnb C-fragments.
// ---------------------------------------------------------------------------
__global__ __launch_bounds__(512, 2)
void gemm2_kernel(const ushort* __restrict__ lnb, const float* __restrict__ feat,
                  const ushort* __restrict__ sWfrag, const float* __restrict__ skipb,
                  float* __restrict__ out) {
    __shared__ __align__(16) ushort Blds[32768];   // 64 KB
    const int tid = threadIdx.x;
    #pragma unroll
    for (int i = 0; i < 8; ++i)
        ((uint4*)Blds)[tid + i * 512] = ((const uint4*)sWfrag)[tid + i * 512];
    __syncthreads();

    const int lane = tid & 63;
    const int c = lane & 15, g = lane >> 4;
    const int gw = blockIdx.x * 8 + (tid >> 6);

    float sb[16];
    #pragma unroll
    for (int n = 0; n < 16; ++n) sb[n] = skipb[n * 16 + c];

    for (int t = gw; t < NT; t += 4096) {
        const int r0 = t * 16;
        bf16x8 A[4];
        #pragma unroll
        for (int ks = 0; ks < 4; ++ks) {
            const float* fp = feat + (size_t)(r0 + c) * IN_DIM + ks * 32 + g * 8;
            float4 u = *(const float4*)fp;
            float4 v = *(const float4*)(fp + 4);
            bf16x8 a;
            a[0] = f2bf(u.x); a[1] = f2bf(u.y); a[2] = f2bf(u.z); a[3] = f2bf(u.w);
            a[4] = f2bf(v.x); a[5] = f2bf(v.y); a[6] = f2bf(v.z); a[7] = f2bf(v.w);
            A[ks] = a;
        }

        f32x4 acc[16];
        #pragma unroll
        for (int n = 0; n < 16; ++n) {
            ushort4 l = *(const ushort4*)(lnb + ((size_t)(t * 16 + n) * 64 + lane) * 4);
            acc[n] = (f32x4){bf2f(l.x), bf2f(l.y), bf2f(l.z), bf2f(l.w)};
            #pragma unroll
            for (int ks = 0; ks < 4; ++ks) {
                bf16x8 b = *(const bf16x8*)(Blds + ((n * 4 + ks) * 64 + lane) * 8);
                acc[n] = __builtin_amdgcn_mfma_f32_16x16x32_bf16(A[ks], b, acc[n], 0, 0, 0);
            }
        }

        #pragma unroll
        for (int n = 0; n < 16; ++n) {
            #pragma unroll
            for (int j = 0; j < 4; ++j)
                out[(size_t)(r0 + g * 4 + j) * HID_DIM + n * 16 + c] = acc[n][j] + sb[n];
        }
    }
}

// ---------------------------------------------------------------------------
extern "C" void kernel_launch(void* const* d_in, const int* in_sizes, int n_in,
                              void* d_out, int out_size, void* d_ws, size_t ws_size,
                              hipStream_t stream) {
    const float* feat  = (const float*)d_in[0];
    const int*   src   = (const int*)d_in[1];
    const int*   dst   = (const int*)d_in[2];
    const float* W     = (const float*)d_in[3];
    const float* bvec  = (const float*)d_in[4];
    const float* gamma = (const float*)d_in[5];
    const float* beta  = (const float*)d_in[6];
    const float* skipW = (const float*)d_in[7];
    const float* skipb = (const float*)d_in[8];
    float* out = (float*)d_out;

    // workspace layout, peak ≈ 77 MB:
    // [Wfrag 64K][sWfrag 64K][aggb 25.6M][X: featn 25.6M | edge_src 6.4M |
    //  deg_out .4M | deg_in .4M | fill .4M | row_ptr .4M]
    // lnb (51.2M, bf16 C-frag) ALIASES X (all X members dead before kernel 7).
    char* ws = (char*)d_ws;
    ushort*   Wfrag    = (ushort*)ws;                              // 64 KB
    ushort*   sWfrag   = Wfrag + 32768;                            // 64 KB
    ushort*   aggb     = sWfrag + 32768;                           // 25.6 MB
    char*     xbase    = (char*)(aggb + (size_t)N_NODES * IN_DIM);
    ushort*   featn    = (ushort*)xbase;                           // 25.6 MB
    unsigned* edge_src = (unsigned*)(featn + (size_t)N_NODES * IN_DIM); // 6.4 MB
    unsigned* deg_out  = edge_src + N_EDGES;                       // N
    unsigned* deg_in   = deg_out + N_NODES;                        // N
    unsigned* fill     = deg_in + N_NODES;                         // N
    unsigned* row_ptr  = fill + N_NODES;                           // N+4
    ushort*   lnb      = (ushort*)xbase;                           // 51.2 MB alias

    hipMemsetAsync(deg_out, 0, (size_t)3 * N_NODES * 4, stream);

    deg_kernel<<<(N_EDGES + 255) / 256, 256, 0, stream>>>(src, dst, deg_out, deg_in);

    wcvt_kernel<<<32, 256, 0, stream>>>(W, skipW, Wfrag, sWfrag);

    scan_kernel<<<1, 1024, 0, stream>>>(deg_in, row_ptr);

    fill_kernel<<<(N_EDGES + 255) / 256, 256, 0, stream>>>(src, dst, row_ptr, fill, edge_src);

    fcvt_kernel<<<(N_NODES * (IN_DIM / 4) + 255) / 256, 256, 0, stream>>>(feat, deg_out, featn);

    spmm_kernel<<<(N_NODES * 64 + 255) / 256, 256, 0, stream>>>(featn, row_ptr, edge_src,
                                                                (unsigned*)aggb);

    gemm1_ln_kernel<<<512, 512, 0, stream>>>(aggb, Wfrag, bvec, gamma, beta, lnb);

    gemm2_kernel<<<512, 512, 0, stream>>>(lnb, feat, sWfrag, skipb, out);
}